// Round 10
// baseline (42.735 us; speedup 1.0000x reference)
//
#include <hip/hip_runtime.h>
#include <hip/hip_bf16.h>

#define B_    4
#define T_    4096
#define D_    2048
#define NTOK  (B_ * T_)
#define NREC  3
#define BAL_W 0.01f
#define Z_W   0.001f
#define ABLK  1024            // phaseA blocks (4096 waves -> whole grid resident)
#define ATHR  256             // 4 waves/block

typedef __attribute__((ext_vector_type(4))) float float4v;

__device__ __forceinline__ void load_tok(const float* __restrict__ xp, int lane,
                                         float4v v[8]) {
#pragma unroll
    for (int j = 0; j < 8; ++j)
        v[j] = __builtin_nontemporal_load(
            reinterpret_cast<const float4v*>(xp + (j * 64 + lane) * 4));
}

// Phase A: persistent grid (fully resident), 4 tokens/wave, depth-1 register
// prefetch (ping-pong A/B buffers): token t+1's loads are in flight while
// token t computes. W staged once per block in LDS. d_out FLOAT32:
//   [0, NTOK)        : selected (phase B)
//   [NTOK, 2*NTOK)   : gate, sign = inactive tag (uncompacted; fixed by B)
//   [2*NTOK, 3*NTOK) : logit0
//   [3*NTOK] aux, [3*NTOK+1] z
__global__ __launch_bounds__(ATHR, 4) void tcr10_phaseA(
    const float* __restrict__ x,              // [NTOK, D_] f32
    const float* __restrict__ w,              // [NREC, D_] f32
    const int* __restrict__ ridx_p,
    float* __restrict__ out_f,                // d_out as f32
    float4v* __restrict__ partials)           // [ABLK] in d_ws
{
    __shared__ float s_w[NREC * D_];          // 24 KB
    {
        const float4v* src = reinterpret_cast<const float4v*>(w);
        float4v*       dst = reinterpret_cast<float4v*>(s_w);
#pragma unroll
        for (int i = 0; i < (NREC * D_ / 4) / ATHR; ++i)   // 6
            dst[i * ATHR + threadIdx.x] =
                __builtin_nontemporal_load(src + i * ATHR + threadIdx.x);
    }
    __syncthreads();

    const int ridx = ridx_p[0];
    const int jc   = ridx < (NREC - 1) ? (ridx < 0 ? 0 : ridx) : (NREC - 1);
    const int lane = threadIdx.x & 63;
    const int wv   = threadIdx.x >> 6;                     // wave in block (0..3)
    const int wid  = (blockIdx.x * ATHR + threadIdx.x) >> 6;
    const int t0   = wid * 4;                              // 4 consecutive tokens

    float z2 = 0.f, c0 = 0.f, c1 = 0.f, c2 = 0.f;

    // process one token whose x-slice is in v[]
    auto process = [&](const float4v v[8], int t) {
        float a0 = 0.f, a1 = 0.f, a2 = 0.f;
#pragma unroll
        for (int j = 0; j < 8; ++j) {
            const int kb = (j * 64 + lane) * 4;
            const float4v w0 = *reinterpret_cast<const float4v*>(&s_w[kb]);
            const float4v w1 = *reinterpret_cast<const float4v*>(&s_w[D_ + kb]);
            const float4v w2 = *reinterpret_cast<const float4v*>(&s_w[2 * D_ + kb]);
#pragma unroll
            for (int e = 0; e < 4; ++e) {
                a0 = fmaf(v[j][e], w0[e], a0);
                a1 = fmaf(v[j][e], w1[e], a1);
                a2 = fmaf(v[j][e], w2[e], a2);
            }
        }
#pragma unroll
        for (int off = 32; off > 0; off >>= 1) {
            a0 += __shfl_xor(a0, off);
            a1 += __shfl_xor(a1, off);
            a2 += __shfl_xor(a2, off);
        }
        if (lane == 0) {
            const float m  = fmaxf(a0, fmaxf(a1, a2));
            const float e0 = expf(a0 - m), e1 = expf(a1 - m), e2 = expf(a2 - m);
            const float s  = e0 + e1 + e2;
            const float z  = m + logf(s);
            int   assign = 0; float best = a0;
            if (a1 > best) { best = a1; assign = 1; }
            if (a2 > best) { best = a2; assign = 2; }
            const float g = (jc == 0 ? e0 : (jc == 1 ? e1 : e2)) / s;   // > 0

            out_f[NTOK + t]     = (assign >= ridx) ? g : -g;  // sign = inactive
            out_f[2 * NTOK + t] = a0;

            z2 += z * z;
            if (assign == 0) c0 += 1.f; else if (assign == 1) c1 += 1.f; else c2 += 1.f;
        }
    };

    const float* xp = x + (size_t)t0 * D_;
    float4v bufA[8], bufB[8];
    load_tok(xp, lane, bufA);                 // t0 in flight
    load_tok(xp + D_, lane, bufB);            // t0+1 in flight
    process(bufA, t0);                        // waits A only; B stays in flight
    load_tok(xp + 2 * (size_t)D_, lane, bufA);// t0+2 in flight
    process(bufB, t0 + 1);
    load_tok(xp + 3 * (size_t)D_, lane, bufB);// t0+3 in flight
    process(bufA, t0 + 2);
    process(bufB, t0 + 3);

    // Block partial reduce (4 waves) -> one float4 per block. No atomics.
    __shared__ float4v s_part[ATHR / 64];
    if (lane == 0) {
        float4v p; p[0] = z2; p[1] = c0; p[2] = c1; p[3] = c2;
        s_part[wv] = p;
    }
    __syncthreads();
    if (threadIdx.x == 0) {
        float4v p = s_part[0];
#pragma unroll
        for (int i = 1; i < ATHR / 64; ++i) {
            const float4v q = s_part[i];
#pragma unroll
            for (int e = 0; e < 4; ++e) p[e] += q[e];
        }
        partials[blockIdx.x] = p;
    }
}

// Phase B: per-batch stable compaction via shuffle-based scan (2 barriers),
// plus loss reduction (block 0) via shuffle reduce.
__global__ __launch_bounds__(1024) void tcr10_phaseB(
    const float4v* __restrict__ partials,     // [ABLK]
    float* __restrict__ out_f)
{
    __shared__ int      s_ws[16];
    __shared__ unsigned s_sel[T_];
    __shared__ float    s_g[T_];
    __shared__ float4v  s_red[16];
    const int b    = blockIdx.x;
    const int tid  = threadIdx.x;
    const int lane = tid & 63;
    const int wv   = tid >> 6;                // 16 waves
    const int base = b * T_;

    float g[4]; int f[4]; int loc = 0;
#pragma unroll
    for (int r = 0; r < 4; ++r) {
        g[r] = out_f[NTOK + base + tid * 4 + r];
        f[r] = (g[r] > 0.f) ? 1 : 0;          // sign set => inactive
        loc += f[r];
    }
    int isc = loc;
#pragma unroll
    for (int off = 1; off < 64; off <<= 1) {
        const int u = __shfl_up(isc, off);
        if (lane >= off) isc += u;
    }
    if (lane == 63) s_ws[wv] = isc;
    __syncthreads();
    int wbase = 0, cnt = 0;
#pragma unroll
    for (int i = 0; i < 16; ++i) {
        const int v = s_ws[i];
        cnt += v;
        if (i < wv) wbase += v;
    }
    int pos = wbase + isc - loc;              // exclusive prefix
#pragma unroll
    for (int r = 0; r < 4; ++r) {
        if (f[r] && (unsigned)pos < (unsigned)T_) {
            s_sel[pos] = (unsigned)(tid * 4 + r);
            s_g[pos]   = g[r];
            ++pos;
        }
    }
    __syncthreads();

#pragma unroll
    for (int r = 0; r < 4; ++r) {
        const int k = tid + r * 1024;         // coalesced
        float selv, gv;
        if (cnt == 0) { selv = 0.f; gv = 0.f; }
        else {
            const int kk = (k < cnt) ? k : (cnt - 1);
            selv = (float)s_sel[kk];
            gv   = s_g[kk];
        }
        out_f[base + k]        = selv;        // selected
        out_f[NTOK + base + k] = gv;          // gate_weights (compacted)
    }

    // Loss reduction: block 0 folds ABLK==1024 partials (one per thread).
    float4v p;
    if (b == 0) p = partials[tid];
    else { p[0] = 0.f; p[1] = 0.f; p[2] = 0.f; p[3] = 0.f; }
#pragma unroll
    for (int off = 32; off > 0; off >>= 1) {
#pragma unroll
        for (int e = 0; e < 4; ++e) p[e] += __shfl_xor(p[e], off);
    }
    if (lane == 0) s_red[wv] = p;
    __syncthreads();
    if (b == 0 && tid == 0) {
        float4v q = s_red[0];
#pragma unroll
        for (int i = 1; i < 16; ++i) {
            const float4v r2 = s_red[i];
#pragma unroll
            for (int e = 0; e < 4; ++e) q[e] += r2[e];
        }
        const float inv = 1.0f / (float)NTOK;
        float aux = 0.f;
#pragma unroll
        for (int n = 0; n < NREC; ++n) {
            const float d = q[1 + n] * inv - (1.0f / 3.0f);
            aux = fmaf(d, d, aux);
        }
        out_f[3 * NTOK + 0] = BAL_W * aux;
        out_f[3 * NTOK + 1] = Z_W * q[0] * inv;
    }
}

extern "C" void kernel_launch(void* const* d_in, const int* in_sizes, int n_in,
                              void* d_out, int out_size, void* d_ws, size_t ws_size,
                              hipStream_t stream) {
    const float* x  = (const float*)d_in[0];
    const float* w  = (const float*)d_in[1];
    const int* ridx = (const int*)d_in[2];
    float* out_f = (float*)d_out;
    float4v* partials = (float4v*)d_ws;   // 16 KB of ws

    tcr10_phaseA<<<dim3(ABLK), dim3(ATHR), 0, stream>>>(x, w, ridx, out_f, partials);
    tcr10_phaseB<<<dim3(B_), dim3(1024), 0, stream>>>(partials, out_f);
}

// Round 11
// 33.057 us; speedup vs baseline: 1.2928x; 1.2928x over previous
//
#include <hip/hip_runtime.h>
#include <hip/hip_bf16.h>

#define B_    4
#define T_    4096
#define D_    2048
#define NTOK  (B_ * T_)
#define NREC  3
#define BAL_W 0.01f
#define Z_W   0.001f
#define ABLK  2048            // K1 blocks
#define ATHR  256             // K1 threads/block (4 waves); 8192 waves, 2 tok/wave
#define FBLK  (NTOK / 256)    // K2 blocks = 64

typedef __attribute__((ext_vector_type(4))) float float4v;

// K1: pure streamer. r9 shape (16 nt-loads up front, W in LDS), but the
// per-token tail is only a 4-step butterfly + partial store: lane L ends
// with sum over lanes ≡ L (mod 4); lanes 0-3 write dots[t*12 + l*3 + n].
// No transcendentals, no lane0-serial epilogue, no full 6-step chain.
__global__ __launch_bounds__(ATHR) void tcr11_stream(
    const float* __restrict__ x,              // [NTOK, D_] f32
    const float* __restrict__ w,              // [NREC, D_] f32
    float* __restrict__ dots)                 // [NTOK*12] in d_ws
{
    __shared__ float s_w[NREC * D_];          // 24 KB
    {
        const float4v* src = reinterpret_cast<const float4v*>(w);
        float4v*       dst = reinterpret_cast<float4v*>(s_w);
#pragma unroll
        for (int i = 0; i < (NREC * D_ / 4) / ATHR; ++i)   // 6
            dst[i * ATHR + threadIdx.x] =
                __builtin_nontemporal_load(src + i * ATHR + threadIdx.x);
    }
    __syncthreads();

    const int lane = threadIdx.x & 63;
    const int wid  = (blockIdx.x * ATHR + threadIdx.x) >> 6;
    const int t0   = wid * 2;                              // tokens t0, t0+1

    const float* xp0 = x + (size_t)t0 * D_;
    float4v xv0[8], xv1[8];
#pragma unroll
    for (int j = 0; j < 8; ++j) {
        xv0[j] = __builtin_nontemporal_load(
            reinterpret_cast<const float4v*>(xp0 + (j * 64 + lane) * 4));
        xv1[j] = __builtin_nontemporal_load(
            reinterpret_cast<const float4v*>(xp0 + D_ + (j * 64 + lane) * 4));
    }

    float a0 = 0.f, a1 = 0.f, a2 = 0.f;       // token t0
    float b0 = 0.f, b1 = 0.f, b2 = 0.f;       // token t0+1
#pragma unroll
    for (int j = 0; j < 8; ++j) {
        const int kb = (j * 64 + lane) * 4;
        const float4v w0 = *reinterpret_cast<const float4v*>(&s_w[kb]);
        const float4v w1 = *reinterpret_cast<const float4v*>(&s_w[D_ + kb]);
        const float4v w2 = *reinterpret_cast<const float4v*>(&s_w[2 * D_ + kb]);
#pragma unroll
        for (int e = 0; e < 4; ++e) {
            a0 = fmaf(xv0[j][e], w0[e], a0);
            a1 = fmaf(xv0[j][e], w1[e], a1);
            a2 = fmaf(xv0[j][e], w2[e], a2);
            b0 = fmaf(xv1[j][e], w0[e], b0);
            b1 = fmaf(xv1[j][e], w1[e], b1);
            b2 = fmaf(xv1[j][e], w2[e], b2);
        }
    }
    // 4-step butterfly over bits 2..5: lane L = sum over lanes with same L&3
#pragma unroll
    for (int off = 4; off < 64; off <<= 1) {
        a0 += __shfl_xor(a0, off);
        a1 += __shfl_xor(a1, off);
        a2 += __shfl_xor(a2, off);
        b0 += __shfl_xor(b0, off);
        b1 += __shfl_xor(b1, off);
        b2 += __shfl_xor(b2, off);
    }
    if (lane < 4) {
        float* d0 = dots + (size_t)t0 * 12 + lane * 3;
        d0[0] = a0; d0[1] = a1; d0[2] = a2;
        float* d1 = dots + (size_t)(t0 + 1) * 12 + lane * 3;
        d1[0] = b0; d1[1] = b1; d1[2] = b2;
    }
}

// K2: finisher. Thread-per-token: 3 coalesced dwordx4 reads of the 12
// partials, softmax/argmax/lse in EVERY lane, signed-gate + logit0 writes,
// block loss-reduce -> partials[FBLK].
__global__ __launch_bounds__(256) void tcr11_finish(
    const float* __restrict__ dots,
    const int* __restrict__ ridx_p,
    float* __restrict__ out_f,
    float4v* __restrict__ partials)           // [FBLK]
{
    const int ridx = ridx_p[0];
    const int jc   = ridx < (NREC - 1) ? (ridx < 0 ? 0 : ridx) : (NREC - 1);
    const int t    = blockIdx.x * 256 + threadIdx.x;
    const int lane = threadIdx.x & 63;
    const int wv   = threadIdx.x >> 6;

    const float4v* dp = reinterpret_cast<const float4v*>(dots + (size_t)t * 12);
    const float4v f0 = dp[0], f1 = dp[1], f2 = dp[2];
    // layout [l][n] (l*3+n): n=0 at 0,3,6,9 ; n=1 at 1,4,7,10 ; n=2 at 2,5,8,11
    const float a0 = (f0[0] + f0[3]) + (f1[2] + f2[1]);
    const float a1 = (f0[1] + f1[0]) + (f1[3] + f2[2]);
    const float a2 = (f0[2] + f1[1]) + (f2[0] + f2[3]);

    const float m  = fmaxf(a0, fmaxf(a1, a2));
    const float e0 = expf(a0 - m), e1 = expf(a1 - m), e2 = expf(a2 - m);
    const float s  = e0 + e1 + e2;
    const float z  = m + logf(s);
    int   assign = 0; float best = a0;
    if (a1 > best) { best = a1; assign = 1; }
    if (a2 > best) { best = a2; assign = 2; }
    const float g = (jc == 0 ? e0 : (jc == 1 ? e1 : e2)) / s;   // > 0 strictly

    out_f[NTOK + t]     = (assign >= ridx) ? g : -g;   // sign = inactive tag
    out_f[2 * NTOK + t] = a0;

    // block loss-reduce: every thread contributes (no divergence)
    float4v p;
    p[0] = z * z;
    p[1] = (assign == 0) ? 1.f : 0.f;
    p[2] = (assign == 1) ? 1.f : 0.f;
    p[3] = (assign == 2) ? 1.f : 0.f;
#pragma unroll
    for (int off = 32; off > 0; off >>= 1) {
#pragma unroll
        for (int e = 0; e < 4; ++e) p[e] += __shfl_xor(p[e], off);
    }
    __shared__ float4v s_part[4];
    if (lane == 0) s_part[wv] = p;
    __syncthreads();
    if (threadIdx.x == 0) {
        float4v q = s_part[0];
#pragma unroll
        for (int i = 1; i < 4; ++i) {
            const float4v r2 = s_part[i];
#pragma unroll
            for (int e = 0; e < 4; ++e) q[e] += r2[e];
        }
        partials[blockIdx.x] = q;
    }
}

// Phase B: per-batch stable compaction via shuffle-based scan (2 barriers),
// plus loss reduction (block 0) over FBLK partials.
__global__ __launch_bounds__(1024) void tcr11_phaseB(
    const float4v* __restrict__ partials,     // [FBLK]
    float* __restrict__ out_f)
{
    __shared__ int      s_ws[16];
    __shared__ unsigned s_sel[T_];
    __shared__ float    s_g[T_];
    __shared__ float4v  s_red[16];
    const int b    = blockIdx.x;
    const int tid  = threadIdx.x;
    const int lane = tid & 63;
    const int wv   = tid >> 6;                // 16 waves
    const int base = b * T_;

    float g[4]; int f[4]; int loc = 0;
#pragma unroll
    for (int r = 0; r < 4; ++r) {
        g[r] = out_f[NTOK + base + tid * 4 + r];
        f[r] = (g[r] > 0.f) ? 1 : 0;          // sign set => inactive
        loc += f[r];
    }
    int isc = loc;
#pragma unroll
    for (int off = 1; off < 64; off <<= 1) {
        const int u = __shfl_up(isc, off);
        if (lane >= off) isc += u;
    }
    if (lane == 63) s_ws[wv] = isc;
    __syncthreads();
    int wbase = 0, cnt = 0;
#pragma unroll
    for (int i = 0; i < 16; ++i) {
        const int v = s_ws[i];
        cnt += v;
        if (i < wv) wbase += v;
    }
    int pos = wbase + isc - loc;              // exclusive prefix
#pragma unroll
    for (int r = 0; r < 4; ++r) {
        if (f[r] && (unsigned)pos < (unsigned)T_) {
            s_sel[pos] = (unsigned)(tid * 4 + r);
            s_g[pos]   = g[r];
            ++pos;
        }
    }
    __syncthreads();

#pragma unroll
    for (int r = 0; r < 4; ++r) {
        const int k = tid + r * 1024;         // coalesced
        float selv, gv;
        if (cnt == 0) { selv = 0.f; gv = 0.f; }
        else {
            const int kk = (k < cnt) ? k : (cnt - 1);
            selv = (float)s_sel[kk];
            gv   = s_g[kk];
        }
        out_f[base + k]        = selv;        // selected
        out_f[NTOK + base + k] = gv;          // gate_weights (compacted)
    }

    // Loss reduction: block 0 folds FBLK==64 partials.
    float4v p;
    if (b == 0 && tid < FBLK) p = partials[tid];
    else { p[0] = 0.f; p[1] = 0.f; p[2] = 0.f; p[3] = 0.f; }
#pragma unroll
    for (int off = 32; off > 0; off >>= 1) {
#pragma unroll
        for (int e = 0; e < 4; ++e) p[e] += __shfl_xor(p[e], off);
    }
    if (lane == 0) s_red[wv] = p;
    __syncthreads();
    if (b == 0 && tid == 0) {
        float4v q = s_red[0];
#pragma unroll
        for (int i = 1; i < 16; ++i) {
            const float4v r2 = s_red[i];
#pragma unroll
            for (int e = 0; e < 4; ++e) q[e] += r2[e];
        }
        const float inv = 1.0f / (float)NTOK;
        float aux = 0.f;
#pragma unroll
        for (int n = 0; n < NREC; ++n) {
            const float d = q[1 + n] * inv - (1.0f / 3.0f);
            aux = fmaf(d, d, aux);
        }
        out_f[3 * NTOK + 0] = BAL_W * aux;
        out_f[3 * NTOK + 1] = Z_W * q[0] * inv;
    }
}

extern "C" void kernel_launch(void* const* d_in, const int* in_sizes, int n_in,
                              void* d_out, int out_size, void* d_ws, size_t ws_size,
                              hipStream_t stream) {
    const float* x  = (const float*)d_in[0];
    const float* w  = (const float*)d_in[1];
    const int* ridx = (const int*)d_in[2];
    float* out_f = (float*)d_out;

    float4v* partials = (float4v*)d_ws;                  // [64]  (1 KB)
    float*   dots     = (float*)d_ws + 1024;             // [NTOK*12] (768 KB)

    tcr11_stream<<<dim3(ABLK), dim3(ATHR), 0, stream>>>(x, w, dots);
    tcr11_finish<<<dim3(FBLK), dim3(256),  0, stream>>>(dots, ridx, out_f, partials);
    tcr11_phaseB<<<dim3(B_),   dim3(1024), 0, stream>>>(partials, out_f);
}